// Round 14
// baseline (160.387 us; speedup 1.0000x reference)
//
#include <hip/hip_runtime.h>

#define NUM_NODES 10000
#define NUM_EDGES 640000
#define D_FEAT 128

// Buckets of 20 nodes: 10000/20 = 500 exactly.
#define NPB 20
#define NB 500
#define K1_BLOCKS 256
#define EPB (NUM_EDGES / K1_BLOCKS)      // 2500 edges per block
// R14 = COUNTER-VISIBILITY ROUND: K2 launched as ONE mega-dispatch of
// 8*NB blocks (block i serves bucket i%500; all 8 reps write identical
// values -> race-free). Single dispatch ~125us > 43us fill threshold ->
// K2's VALUBusy/Occupancy/LDS_CONFLICT/FETCH finally visible in top-5.
// LESSONS: R4 global-atomic binning 195us. R7/R11: floor ~57us, K1 ~8,
// K2 ~16. R8/R10/R12/R13: FIVE structural K2 edits all null (+-1us) ->
// model is wrong somewhere; buy counters before more edits.
#define CELL_CAP 16
#define MAXB 1792
#define INV 0xFFFFFFFFu
#define ZROW 10000u                      // zero row index in xb

// x in bf16: one row = 128 bf16 = 256 B = 16 uint4. +16 for the zero row.
#define XB_U4 (NUM_NODES * 16 + 16)
#define CVT_PER_BLOCK (NUM_NODES * 16 / K1_BLOCKS)  // 625 uint4 per block

// ---------------------------------------------------------------------------
// Workspace (d_ws):
//   xb      [XB_U4]                uint4 -- x in bf16 + zero row (2.56 MB)
//   ovfcell [K1_BLOCKS*16]         u32   -- entries[0..14] + count[15] (16 KB)
//   slots   [NB*K1_BLOCKS*CELL_CAP]u32   -- sentinel cells (8.19 MB)
// ---------------------------------------------------------------------------

__device__ __forceinline__ unsigned bf16_rne(float f) {
    unsigned u = __float_as_uint(f);
    return (u + 0x7FFFu + ((u >> 16) & 1u)) >> 16;
}

__device__ __forceinline__ int div20(int d) {
    return (int)(((unsigned)d * 104858u) >> 21);
}

// K1: identical to R13.
__global__ __launch_bounds__(1024) void scatter_cvt_kernel(
    const int* __restrict__ ei, const float4* __restrict__ x4,
    uint4* __restrict__ xb, unsigned* __restrict__ ovfcell,
    uint4* __restrict__ slots4)
{
    __shared__ int cur[NB];
    __shared__ uint4 cellsv[NB * (CELL_CAP / 4)];   // 32 KB
    __shared__ unsigned s_ovf[15];
    __shared__ int ovfcur;

    int t = threadIdx.x, b = blockIdx.x;
    if (t < NB) cur[t] = 0;
    if (t < 15) s_ovf[t] = 0;
    if (t == 0) ovfcur = 0;
    uint4 iv = make_uint4(INV, INV, INV, INV);
    if (t < 1000) { cellsv[t] = iv; cellsv[t + 1000] = iv; }

    int base = b * EPB;
    int s0 = ei[base + t];
    int d0 = ei[NUM_EDGES + base + t];
    int s1 = ei[base + t + 1024];
    int d1 = ei[NUM_EDGES + base + t + 1024];
    int s2 = 0, d2 = 0;
    bool has2 = (t + 2048) < EPB;
    if (has2) {
        s2 = ei[base + t + 2048];
        d2 = ei[NUM_EDGES + base + t + 2048];
    }

    if (t < CVT_PER_BLOCK) {
        int o = b * CVT_PER_BLOCK + t;
        float4 a = x4[2 * o];
        float4 c = x4[2 * o + 1];
        uint4 w;
        w.x = bf16_rne(a.x) | (bf16_rne(a.y) << 16);
        w.y = bf16_rne(a.z) | (bf16_rne(a.w) << 16);
        w.z = bf16_rne(c.x) | (bf16_rne(c.y) << 16);
        w.w = bf16_rne(c.z) | (bf16_rne(c.w) << 16);
        xb[o] = w;
    }
    if (b == 0 && t < 16)
        xb[NUM_NODES * 16 + t] = make_uint4(0u, 0u, 0u, 0u);
    __syncthreads();

    unsigned* cells = (unsigned*)cellsv;
    {
        int k = div20(d0), m = d0 - k * NPB;
        int pos = atomicAdd(&cur[k], 1);
        if (pos < CELL_CAP)
            cells[k * CELL_CAP + pos] = ((unsigned)m << 16) | (unsigned)s0;
        else {
            int o = atomicAdd(&ovfcur, 1);
            if (o < 15) s_ovf[o] = ((unsigned)k << 19) |
                                   ((unsigned)m << 14) | (unsigned)s0;
        }
    }
    {
        int k = div20(d1), m = d1 - k * NPB;
        int pos = atomicAdd(&cur[k], 1);
        if (pos < CELL_CAP)
            cells[k * CELL_CAP + pos] = ((unsigned)m << 16) | (unsigned)s1;
        else {
            int o = atomicAdd(&ovfcur, 1);
            if (o < 15) s_ovf[o] = ((unsigned)k << 19) |
                                   ((unsigned)m << 14) | (unsigned)s1;
        }
    }
    if (has2) {
        int k = div20(d2), m = d2 - k * NPB;
        int pos = atomicAdd(&cur[k], 1);
        if (pos < CELL_CAP)
            cells[k * CELL_CAP + pos] = ((unsigned)m << 16) | (unsigned)s2;
        else {
            int o = atomicAdd(&ovfcur, 1);
            if (o < 15) s_ovf[o] = ((unsigned)k << 19) |
                                   ((unsigned)m << 14) | (unsigned)s2;
        }
    }
    __syncthreads();

    for (int idx = t; idx < NB * (CELL_CAP / 4); idx += 1024)
        slots4[((unsigned)(idx >> 2) * K1_BLOCKS + (unsigned)b) *
               (CELL_CAP / 4) + (unsigned)(idx & 3)] = cellsv[idx];
    if (t < 15) ovfcell[b * 16 + t] = s_ovf[t];
    if (t == 15) ovfcell[b * 16 + 15] = (unsigned)min(ovfcur, 15);
}

__device__ __forceinline__ void acc8(float* a, uint4 w) {
    a[0] += __uint_as_float(w.x << 16);
    a[1] += __uint_as_float(w.x & 0xFFFF0000u);
    a[2] += __uint_as_float(w.y << 16);
    a[3] += __uint_as_float(w.y & 0xFFFF0000u);
    a[4] += __uint_as_float(w.z << 16);
    a[5] += __uint_as_float(w.z & 0xFFFF0000u);
    a[6] += __uint_as_float(w.w << 16);
    a[7] += __uint_as_float(w.w & 0xFFFF0000u);
}

__device__ __forceinline__ void reduce_write(float* a, int node, int q, int sub,
                                             float4* __restrict__ out4) {
    #pragma unroll
    for (int r = 0; r < 8; ++r) {
        a[r] += __shfl_down(a[r], 32);
        a[r] += __shfl_down(a[r], 16);
    }
    if (q == 0) {
        unsigned o = (unsigned)node * 32u + (unsigned)sub * 2u;
        out4[o]     = make_float4(a[0], a[1], a[2], a[3]);
        out4[o + 1] = make_float4(a[4], a[5], a[6], a[7]);
    }
}

// K2: R13's kernel, launched with 8*NB blocks; bucket = blockIdx % NB.
// All 8 reps compute identical results; duplicate identical stores to out
// are race-free by value. Mega-dispatch duration ~125us -> visible counters.
__global__ __launch_bounds__(640, 5) void sort_gather_kernel(
    const uint4* __restrict__ xb,
    const uint4* __restrict__ slots4,
    const unsigned* __restrict__ ovfcell,
    float4* __restrict__ out4)
{
    __shared__ unsigned s_src[MAXB];
    __shared__ int h[NPB];
    __shared__ int off20[NPB];
    __shared__ int cur20[NPB];
    __shared__ int s_ovfany;

    int k = blockIdx.x % NB;          // 8 reps per bucket
    int t = threadIdx.x;

    if (t < NPB) h[t] = 0;
    if (t == 0) s_ovfany = 0;
    for (int i = t; i < MAXB; i += 640) s_src[i] = ZROW;

    if (t < K1_BLOCKS) {
        unsigned oc = ovfcell[t * 16 + 15];
        if (oc) atomicOr(&s_ovfany, 1);
    }

    const uint4* sb = slots4 + (unsigned)k * 1024u;
    uint4 w40 = sb[t];
    uint4 w41 = (t < 384) ? sb[t + 640] : make_uint4(INV, INV, INV, INV);
    __syncthreads();

    {
        unsigned m;
        m = w40.x >> 16; if (m < NPB) atomicAdd(&h[m], 1);
        m = w40.y >> 16; if (m < NPB) atomicAdd(&h[m], 1);
        m = w40.z >> 16; if (m < NPB) atomicAdd(&h[m], 1);
        m = w40.w >> 16; if (m < NPB) atomicAdd(&h[m], 1);
        m = w41.x >> 16; if (m < NPB) atomicAdd(&h[m], 1);
        m = w41.y >> 16; if (m < NPB) atomicAdd(&h[m], 1);
        m = w41.z >> 16; if (m < NPB) atomicAdd(&h[m], 1);
        m = w41.w >> 16; if (m < NPB) atomicAdd(&h[m], 1);
    }
    if (s_ovfany && t < K1_BLOCKS) {
        int oc = (int)min(ovfcell[t * 16 + 15], 15u);
        for (int i = 0; i < oc; ++i) {
            unsigned e = ovfcell[t * 16 + i];
            if ((int)(e >> 19) == k) atomicAdd(&h[(e >> 14) & 31u], 1);
        }
    }
    __syncthreads();

    if (t < 32) {
        int val = (t < NPB) ? (((h[t] + 3) & ~3) + 4) : 0;
        int s = val;
        #pragma unroll
        for (int d = 1; d < 32; d <<= 1) {
            int u = __shfl_up(s, d, 32);
            if (t >= d) s += u;
        }
        if (t < NPB) { off20[t] = s - val; cur20[t] = s - val; }
    }
    __syncthreads();

    {
        unsigned m;
        m = w40.x >> 16; if (m < NPB) { int p = atomicAdd(&cur20[m], 1); if (p < MAXB) s_src[p] = w40.x & 0xFFFFu; }
        m = w40.y >> 16; if (m < NPB) { int p = atomicAdd(&cur20[m], 1); if (p < MAXB) s_src[p] = w40.y & 0xFFFFu; }
        m = w40.z >> 16; if (m < NPB) { int p = atomicAdd(&cur20[m], 1); if (p < MAXB) s_src[p] = w40.z & 0xFFFFu; }
        m = w40.w >> 16; if (m < NPB) { int p = atomicAdd(&cur20[m], 1); if (p < MAXB) s_src[p] = w40.w & 0xFFFFu; }
        m = w41.x >> 16; if (m < NPB) { int p = atomicAdd(&cur20[m], 1); if (p < MAXB) s_src[p] = w41.x & 0xFFFFu; }
        m = w41.y >> 16; if (m < NPB) { int p = atomicAdd(&cur20[m], 1); if (p < MAXB) s_src[p] = w41.y & 0xFFFFu; }
        m = w41.z >> 16; if (m < NPB) { int p = atomicAdd(&cur20[m], 1); if (p < MAXB) s_src[p] = w41.z & 0xFFFFu; }
        m = w41.w >> 16; if (m < NPB) { int p = atomicAdd(&cur20[m], 1); if (p < MAXB) s_src[p] = w41.w & 0xFFFFu; }
    }
    if (s_ovfany && t < K1_BLOCKS) {
        int oc = (int)min(ovfcell[t * 16 + 15], 15u);
        for (int i = 0; i < oc; ++i) {
            unsigned e = ovfcell[t * 16 + i];
            if ((int)(e >> 19) == k) {
                int p = atomicAdd(&cur20[(e >> 14) & 31u], 1);
                if (p < MAXB) s_src[p] = e & 0x3FFFu;
            }
        }
    }
    __syncthreads();

    int wave = t >> 6;
    int lane = t & 63;
    int q    = lane >> 4;
    int sub  = lane & 15;

    {
        int m = wave;
        int bA = off20[m];
        int eA = (h[m] + 3) & ~3;
        float a[8] = {0.f, 0.f, 0.f, 0.f, 0.f, 0.f, 0.f, 0.f};
        unsigned s = s_src[bA + q];
        uint4 r = xb[s * 16u + (unsigned)sub];
        for (int j = 0; j < eA; j += 4) {
            unsigned s2 = s_src[bA + j + 4 + q];
            uint4 r2 = xb[s2 * 16u + (unsigned)sub];
            acc8(a, r);
            r = r2;
        }
        reduce_write(a, k * NPB + m, q, sub, out4);
    }
    {
        int m = wave + 10;
        int bB = off20[m];
        int eB = (h[m] + 3) & ~3;
        float a[8] = {0.f, 0.f, 0.f, 0.f, 0.f, 0.f, 0.f, 0.f};
        unsigned s = s_src[bB + q];
        uint4 r = xb[s * 16u + (unsigned)sub];
        for (int j = 0; j < eB; j += 4) {
            unsigned s2 = s_src[bB + j + 4 + q];
            uint4 r2 = xb[s2 * 16u + (unsigned)sub];
            acc8(a, r);
            r = r2;
        }
        reduce_write(a, k * NPB + m, q, sub, out4);
    }
}

extern "C" void kernel_launch(void* const* d_in, const int* in_sizes, int n_in,
                              void* d_out, int out_size, void* d_ws, size_t ws_size,
                              hipStream_t stream) {
    const float* x   = (const float*)d_in[0];   // [10000, 128] f32
    const int*   ei  = (const int*)d_in[1];     // [2, 640000] int32
    float*       out = (float*)d_out;           // [10000, 128] f32

    uint4*    xb      = (uint4*)d_ws;                        // 2.56 MB (+zero row)
    unsigned* ovfcell = (unsigned*)(xb + XB_U4);             // 16 KB
    uint4*    slots4  = (uint4*)(ovfcell + K1_BLOCKS * 16);  // 8.19 MB

    scatter_cvt_kernel<<<K1_BLOCKS, 1024, 0, stream>>>(
        ei, (const float4*)x, xb, ovfcell, slots4);

    // MEGA-K2: 8 reps in one dispatch (~125us) -> visible in rocprof top-5.
    sort_gather_kernel<<<8 * NB, 640, 0, stream>>>(
        xb, (const uint4*)slots4, ovfcell, (float4*)out);
}

// Round 15
// 80.806 us; speedup vs baseline: 1.9848x; 1.9848x over previous
//
#include <hip/hip_runtime.h>

#define NUM_NODES 10000
#define NUM_EDGES 640000
#define D_FEAT 128

// Buckets of 20 nodes: 10000/20 = 500 exactly.
#define NPB 20
#define NB 500
#define K1_BLOCKS 256
#define EPB (NUM_EDGES / K1_BLOCKS)      // 2500 edges per block
// R15 (counter-guided, from R14's mega-K2 profile: VALUBusy 44.7%, occupancy
// 52.6%, HBM 5%, LDS-conflict 2.5% -- no saturated pipe, so DELETE work):
//  - fixed per-node stripes (112 entries) replace histogram+scan+2 barriers;
//    compact atomicAdds into stripe cursors; trip count = cursor - base.
//    In-degree ~ Poisson(64), max ~98 << 108 cap; never-taken wave-cooperative
//    re-scan slow path keeps correctness exact (cells are self-describing).
//  - float2 ext_vector accumulators -> v_pk_add_f32 (8 adds -> 4 per uint4).
// LESSONS: R4 global-atomic binning 195us. R7/R11: floor ~57us, K1 ~8,
// K2 ~13-16. R8/R10/R12/R13: five structural K2 edits null (each hit a ~20%
// slice). R14: K2 is mixed VALU+stall, grid-capped occupancy.
#define CELL_CAP 16
#define INV 0xFFFFFFFFu
#define ZROW 10000u                      // zero row index in xb
#define STRIPE 112                       // per-node stripe in s_src
#define SCAP 108                         // writable cap (rest = pad quads)
#define MAXB (NPB * STRIPE)              // 2240 words = 8.96 KB

// x in bf16: one row = 128 bf16 = 256 B = 16 uint4. +16 for the zero row.
#define XB_U4 (NUM_NODES * 16 + 16)
#define CVT_PER_BLOCK (NUM_NODES * 16 / K1_BLOCKS)  // 625 uint4 per block

typedef __attribute__((ext_vector_type(2))) float f32x2;

// ---------------------------------------------------------------------------
// Workspace (d_ws):
//   xb      [XB_U4]                uint4 -- x in bf16 + zero row (2.56 MB)
//   ovfcell [K1_BLOCKS*16]         u32   -- entries[0..14] + count[15] (16 KB)
//   slots   [NB*K1_BLOCKS*CELL_CAP]u32   -- sentinel cells (8.19 MB)
// ---------------------------------------------------------------------------

__device__ __forceinline__ unsigned bf16_rne(float f) {
    unsigned u = __float_as_uint(f);
    return (u + 0x7FFFu + ((u >> 16) & 1u)) >> 16;
}

__device__ __forceinline__ int div20(int d) {
    // exact floor(d/20) for 0 <= d < 262144 (Granlund-Montgomery)
    return (int)(((unsigned)d * 104858u) >> 21);
}

// K1: identical to R13 (fused cvt + sentinel LDS cells + coalesced write-out).
__global__ __launch_bounds__(1024) void scatter_cvt_kernel(
    const int* __restrict__ ei, const float4* __restrict__ x4,
    uint4* __restrict__ xb, unsigned* __restrict__ ovfcell,
    uint4* __restrict__ slots4)
{
    __shared__ int cur[NB];
    __shared__ uint4 cellsv[NB * (CELL_CAP / 4)];   // 32 KB
    __shared__ unsigned s_ovf[15];
    __shared__ int ovfcur;

    int t = threadIdx.x, b = blockIdx.x;
    if (t < NB) cur[t] = 0;
    if (t < 15) s_ovf[t] = 0;
    if (t == 0) ovfcur = 0;
    uint4 iv = make_uint4(INV, INV, INV, INV);
    if (t < 1000) { cellsv[t] = iv; cellsv[t + 1000] = iv; }

    int base = b * EPB;
    int s0 = ei[base + t];
    int d0 = ei[NUM_EDGES + base + t];
    int s1 = ei[base + t + 1024];
    int d1 = ei[NUM_EDGES + base + t + 1024];
    int s2 = 0, d2 = 0;
    bool has2 = (t + 2048) < EPB;
    if (has2) {
        s2 = ei[base + t + 2048];
        d2 = ei[NUM_EDGES + base + t + 2048];
    }

    if (t < CVT_PER_BLOCK) {
        int o = b * CVT_PER_BLOCK + t;
        float4 a = x4[2 * o];
        float4 c = x4[2 * o + 1];
        uint4 w;
        w.x = bf16_rne(a.x) | (bf16_rne(a.y) << 16);
        w.y = bf16_rne(a.z) | (bf16_rne(a.w) << 16);
        w.z = bf16_rne(c.x) | (bf16_rne(c.y) << 16);
        w.w = bf16_rne(c.z) | (bf16_rne(c.w) << 16);
        xb[o] = w;
    }
    if (b == 0 && t < 16)
        xb[NUM_NODES * 16 + t] = make_uint4(0u, 0u, 0u, 0u);
    __syncthreads();

    unsigned* cells = (unsigned*)cellsv;
    {
        int k = div20(d0), m = d0 - k * NPB;
        int pos = atomicAdd(&cur[k], 1);
        if (pos < CELL_CAP)
            cells[k * CELL_CAP + pos] = ((unsigned)m << 16) | (unsigned)s0;
        else {
            int o = atomicAdd(&ovfcur, 1);
            if (o < 15) s_ovf[o] = ((unsigned)k << 19) |
                                   ((unsigned)m << 14) | (unsigned)s0;
        }
    }
    {
        int k = div20(d1), m = d1 - k * NPB;
        int pos = atomicAdd(&cur[k], 1);
        if (pos < CELL_CAP)
            cells[k * CELL_CAP + pos] = ((unsigned)m << 16) | (unsigned)s1;
        else {
            int o = atomicAdd(&ovfcur, 1);
            if (o < 15) s_ovf[o] = ((unsigned)k << 19) |
                                   ((unsigned)m << 14) | (unsigned)s1;
        }
    }
    if (has2) {
        int k = div20(d2), m = d2 - k * NPB;
        int pos = atomicAdd(&cur[k], 1);
        if (pos < CELL_CAP)
            cells[k * CELL_CAP + pos] = ((unsigned)m << 16) | (unsigned)s2;
        else {
            int o = atomicAdd(&ovfcur, 1);
            if (o < 15) s_ovf[o] = ((unsigned)k << 19) |
                                   ((unsigned)m << 14) | (unsigned)s2;
        }
    }
    __syncthreads();

    for (int idx = t; idx < NB * (CELL_CAP / 4); idx += 1024)
        slots4[((unsigned)(idx >> 2) * K1_BLOCKS + (unsigned)b) *
               (CELL_CAP / 4) + (unsigned)(idx & 3)] = cellsv[idx];
    if (t < 15) ovfcell[b * 16 + t] = s_ovf[t];
    if (t == 15) ovfcell[b * 16 + 15] = (unsigned)min(ovfcur, 15);
}

__device__ __forceinline__ void acc8p(f32x2* a, uint4 w) {
    f32x2 v;
    v.x = __uint_as_float(w.x << 16);
    v.y = __uint_as_float(w.x & 0xFFFF0000u);
    a[0] += v;
    v.x = __uint_as_float(w.y << 16);
    v.y = __uint_as_float(w.y & 0xFFFF0000u);
    a[1] += v;
    v.x = __uint_as_float(w.z << 16);
    v.y = __uint_as_float(w.z & 0xFFFF0000u);
    a[2] += v;
    v.x = __uint_as_float(w.w << 16);
    v.y = __uint_as_float(w.w & 0xFFFF0000u);
    a[3] += v;
}

// K2: no histogram, no scan, 2 barriers (was 4). Fixed stripes + pk adds.
__global__ __launch_bounds__(640, 5) void sort_gather_kernel(
    const uint4* __restrict__ xb,            // [XB_U4] bf16 rows + zero row
    const uint4* __restrict__ slots4,        // sentinel cells
    const unsigned* __restrict__ ovfcell,    // [K1_BLOCKS*16]
    float4* __restrict__ out4)               // [NUM_NODES*32]
{
    __shared__ unsigned s_src[MAXB];
    __shared__ int cur20[NPB];
    __shared__ int s_ovfany;

    int k = blockIdx.x;
    int t = threadIdx.x;

    if (t < NPB) cur20[t] = t * STRIPE;      // fixed stripe base = cursor init
    if (t == 0) s_ovfany = 0;
    for (int i = t; i < MAXB; i += 640) s_src[i] = ZROW;   // pads = zero row

    // K1-overflow gate: 256 count words, L2-hot, almost always all zero
    if (t < K1_BLOCKS) {
        unsigned oc = ovfcell[t * 16 + 15];
        if (oc) atomicOr(&s_ovfany, 1);
    }

    // bucket's 256 cells = 1024 uint4, 2 coalesced rounds (pre-barrier)
    const uint4* sb = slots4 + (unsigned)k * 1024u;
    uint4 w40 = sb[t];
    uint4 w41 = (t < 384) ? sb[t + 640] : make_uint4(INV, INV, INV, INV);
    __syncthreads();

    // compact into fixed stripes; valid iff m-field < NPB (sentinel fails)
    {
        unsigned m;
        m = w40.x >> 16; if (m < NPB) { int p = atomicAdd(&cur20[m], 1); if (p < (int)(m * STRIPE + SCAP)) s_src[p] = w40.x & 0xFFFFu; }
        m = w40.y >> 16; if (m < NPB) { int p = atomicAdd(&cur20[m], 1); if (p < (int)(m * STRIPE + SCAP)) s_src[p] = w40.y & 0xFFFFu; }
        m = w40.z >> 16; if (m < NPB) { int p = atomicAdd(&cur20[m], 1); if (p < (int)(m * STRIPE + SCAP)) s_src[p] = w40.z & 0xFFFFu; }
        m = w40.w >> 16; if (m < NPB) { int p = atomicAdd(&cur20[m], 1); if (p < (int)(m * STRIPE + SCAP)) s_src[p] = w40.w & 0xFFFFu; }
        m = w41.x >> 16; if (m < NPB) { int p = atomicAdd(&cur20[m], 1); if (p < (int)(m * STRIPE + SCAP)) s_src[p] = w41.x & 0xFFFFu; }
        m = w41.y >> 16; if (m < NPB) { int p = atomicAdd(&cur20[m], 1); if (p < (int)(m * STRIPE + SCAP)) s_src[p] = w41.y & 0xFFFFu; }
        m = w41.z >> 16; if (m < NPB) { int p = atomicAdd(&cur20[m], 1); if (p < (int)(m * STRIPE + SCAP)) s_src[p] = w41.z & 0xFFFFu; }
        m = w41.w >> 16; if (m < NPB) { int p = atomicAdd(&cur20[m], 1); if (p < (int)(m * STRIPE + SCAP)) s_src[p] = w41.w & 0xFFFFu; }
    }
    if (s_ovfany && t < K1_BLOCKS) {         // never in practice
        int oc = (int)min(ovfcell[t * 16 + 15], 15u);
        for (int i = 0; i < oc; ++i) {
            unsigned e = ovfcell[t * 16 + i];
            if ((int)(e >> 19) == k) {
                unsigned m = (e >> 14) & 31u;
                int p = atomicAdd(&cur20[m], 1);
                if (p < (int)(m * STRIPE + SCAP)) s_src[p] = e & 0x3FFFu;
            }
        }
    }
    __syncthreads();

    int wave = t >> 6;          // 0..9
    int lane = t & 63;
    int q    = lane >> 4;       // which edge of the quad
    int sub  = lane & 15;       // 16 B chunk (8 bf16) within the row

    #pragma unroll
    for (int half = 0; half < 2; ++half) {
        int m = wave + half * 10;
        int ecRaw = cur20[m] - m * STRIPE;
        f32x2 a[4];
        a[0] = 0.f; a[1] = 0.f; a[2] = 0.f; a[3] = 0.f;

        if (ecRaw <= SCAP) {
            // fast path: mask-free, clamp-free (pads are the zero row)
            int bA = m * STRIPE;
            int eA = (ecRaw + 3) & ~3;
            unsigned s = s_src[bA + q];
            uint4 r = xb[s * 16u + (unsigned)sub];
            for (int j = 0; j < eA; j += 4) {
                unsigned s2 = s_src[bA + j + 4 + q];   // pad quad: safe
                uint4 r2 = xb[s2 * 16u + (unsigned)sub];
                acc8p(a, r);
                r = r2;
            }
        } else {
            // stripe overflow (P ~ 1e-4 on random data; never on this set):
            // wave-cooperative re-scan of the bucket's self-describing cells.
            const unsigned* sw = (const unsigned*)sb;
            for (int idx = q; idx < K1_BLOCKS * CELL_CAP; idx += 4) {
                unsigned w = sw[idx];
                if ((w >> 16) == (unsigned)m) {
                    uint4 r = xb[(w & 0xFFFFu) * 16u + (unsigned)sub];
                    acc8p(a, r);
                }
            }
            if (s_ovfany && q == 0) {
                for (int bb = 0; bb < K1_BLOCKS; ++bb) {
                    int oc = (int)min(ovfcell[bb * 16 + 15], 15u);
                    for (int i = 0; i < oc; ++i) {
                        unsigned e = ovfcell[bb * 16 + i];
                        if ((int)(e >> 19) == k &&
                            (int)((e >> 14) & 31u) == m) {
                            uint4 r = xb[(e & 0x3FFFu) * 16u + (unsigned)sub];
                            acc8p(a, r);
                        }
                    }
                }
            }
        }

        #pragma unroll
        for (int r = 0; r < 4; ++r) {
            a[r].x += __shfl_down(a[r].x, 32);
            a[r].y += __shfl_down(a[r].y, 32);
            a[r].x += __shfl_down(a[r].x, 16);
            a[r].y += __shfl_down(a[r].y, 16);
        }
        if (q == 0) {
            unsigned o = (unsigned)(k * NPB + m) * 32u + (unsigned)sub * 2u;
            out4[o]     = make_float4(a[0].x, a[0].y, a[1].x, a[1].y);
            out4[o + 1] = make_float4(a[2].x, a[2].y, a[3].x, a[3].y);
        }
    }
}

extern "C" void kernel_launch(void* const* d_in, const int* in_sizes, int n_in,
                              void* d_out, int out_size, void* d_ws, size_t ws_size,
                              hipStream_t stream) {
    const float* x   = (const float*)d_in[0];   // [10000, 128] f32
    const int*   ei  = (const int*)d_in[1];     // [2, 640000] int32
    float*       out = (float*)d_out;           // [10000, 128] f32

    uint4*    xb      = (uint4*)d_ws;                        // 2.56 MB (+zero row)
    unsigned* ovfcell = (unsigned*)(xb + XB_U4);             // 16 KB
    uint4*    slots4  = (uint4*)(ovfcell + K1_BLOCKS * 16);  // 8.19 MB

    // K1: convert x -> bf16 + sentinel-cell scatter + coalesced write-out
    scatter_cvt_kernel<<<K1_BLOCKS, 1024, 0, stream>>>(
        ei, (const float4*)x, xb, ovfcell, slots4);

    // K2: fixed-stripe compact (no hist/scan) + clamp-free pk-add gather
    sort_gather_kernel<<<NB, 640, 0, stream>>>(
        xb, (const uint4*)slots4, ovfcell, (float4*)out);
}